// Round 14
// baseline (189.698 us; speedup 1.0000x reference)
//
#include <hip/hip_runtime.h>

typedef __bf16 bf16x8 __attribute__((ext_vector_type(8)));
typedef __bf16 bf16x4 __attribute__((ext_vector_type(4)));
typedef float f32x4 __attribute__((ext_vector_type(4)));
typedef float f32x16 __attribute__((ext_vector_type(16)));

__device__ __forceinline__ f32x4 mfma16(bf16x8 a, bf16x8 b, f32x4 c) {
  return __builtin_amdgcn_mfma_f32_16x16x32_bf16(a, b, c, 0, 0, 0);
}
__device__ __forceinline__ f32x16 mfma32(bf16x8 a, bf16x8 b, f32x16 c) {
  return __builtin_amdgcn_mfma_f32_32x32x16_bf16(a, b, c, 0, 0, 0);
}

// pack 2 fp32 -> u32 of 2 bf16 (compiler fuses to v_cvt_pk_bf16_f32)
__device__ __forceinline__ unsigned int cvtpk(float a, float b) {
  union { __bf16 h[2]; unsigned int u; } r;
  r.h[0] = (__bf16)a; r.h[1] = (__bf16)b;
  return r.u;
}
// v_permlane32_swap_b32: exchange across the 32-lane halves
__device__ __forceinline__ void swap32(unsigned int &a, unsigned int &b) {
  asm("v_permlane32_swap_b32 %0, %1" : "+v"(a), "+v"(b));
}

// Barrier that does NOT drain vmcnt: LDS ops fenced (lgkmcnt(0)), global
// prefetches (K regs, V stage loads) stay in flight across it (T4/T14).
__device__ __forceinline__ void sync_lds() {
  asm volatile("s_waitcnt lgkmcnt(0)" ::: "memory");
  __builtin_amdgcn_s_barrier();
}

// exp2 + rowsum + cvt_pk/permlane pack: S^T f32x16 -> two PV A-fragments
__device__ __forceinline__ void pack_tile(const f32x16 s, float &rs,
                                          bf16x8 &A0v, bf16x8 &A1v) {
  float p[16];
#pragma unroll
  for (int r = 0; r < 16; r++) { p[r] = exp2f(s[r]); rs += p[r]; }
  unsigned int a0 = cvtpk(p[0], p[1]), a1 = cvtpk(p[2], p[3]);
  unsigned int a2 = cvtpk(p[4], p[5]), a3 = cvtpk(p[6], p[7]);
  swap32(a0, a2); swap32(a1, a3);
  unsigned int a4 = cvtpk(p[8], p[9]), a5 = cvtpk(p[10], p[11]);
  unsigned int a6 = cvtpk(p[12], p[13]), a7 = cvtpk(p[14], p[15]);
  swap32(a4, a6); swap32(a5, a7);
  union { unsigned int u[4]; bf16x8 v; } A0, A1;
  A0.u[0] = a0; A0.u[1] = a1; A0.u[2] = a2; A0.u[3] = a3;
  A1.u[0] = a4; A1.u[1] = a5; A1.u[2] = a6; A1.u[3] = a7;
  A0v = A0.v; A1v = A1.v;
}

// ---------------------------------------------------------------------------
// K0: convert Wf(32x256) | Wg(32x256) | Wh(256x256) fp32 -> Wb bf16 [320][256]
// ---------------------------------------------------------------------------
__global__ void wcvt_kernel(const float* __restrict__ Wf, const float* __restrict__ Wg,
                            const float* __restrict__ Wh, __bf16* __restrict__ Wb) {
  int i = blockIdx.x * 256 + threadIdx.x;  // 0..81919
  float v;
  if (i < 8192)       v = Wf[i];
  else if (i < 16384) v = Wg[i - 8192];
  else                v = Wh[i - 16384];
  Wb[i] = (__bf16)v;
}

// ---------------------------------------------------------------------------
// K1: projections.
//   o<64  -> QK_pk[b][nt(128)][qk(2)][frag(2)][h(2)][r(32)][e(8)] bf16
//   o>=64 -> V_pk[b][jc(256)][h(2)][c(256)][e(8)] bf16 (via LDS transpose)
// K features (o in [32,64)) scaled by log2(e) at store: attn uses raw exp2.
// ---------------------------------------------------------------------------
__global__ __launch_bounds__(512) void proj_kernel(
    const float* __restrict__ x, const float* __restrict__ bfv,
    const float* __restrict__ bgv, const float* __restrict__ bhv,
    const __bf16* __restrict__ Wb, __bf16* __restrict__ qkpk,
    __bf16* __restrict__ vpk) {
  __shared__ __align__(16) char smem[2560 + 18432];
  __bf16* xT = (__bf16*)smem;           // [32 n][40 c] bf16
  __bf16* ho = (__bf16*)(smem + 2560);  // [256 c][36 n] bf16

  const int t = threadIdx.x;
  const int l = t & 63, wg = t >> 6, q = l >> 4, l15 = l & 15;
  const int nh = wg & 1, oh = wg >> 1;   // oh 0..3
  const int bi = blockIdx.x;
  const int b = bi >> 7;
  const int nt = bi & 127;               // 32-row n tile
  const int n0 = nt << 5;

  const float* xb = x + (size_t)b * 256 * 4096;

  f32x4 acc[5];
#pragma unroll
  for (int i = 0; i < 5; i++) acc[i] = (f32x4){0.f, 0.f, 0.f, 0.f};

  const int c_rel = t >> 4;        // 0..31
  const int n2 = (t & 15) * 2;     // 0..30

#pragma unroll 1
  for (int kc = 0; kc < 8; kc++) {
    __syncthreads();
    float2 v = *(const float2*)(xb + (size_t)(kc * 32 + c_rel) * 4096 + n0 + n2);
    xT[(n2 + 0) * 40 + c_rel] = (__bf16)v.x;
    xT[(n2 + 1) * 40 + c_rel] = (__bf16)v.y;
    __syncthreads();
    bf16x8 af = *(const bf16x8*)(xT + (nh * 16 + l15) * 40 + q * 8);
    const __bf16* wp = Wb + (size_t)(oh * 80 + l15) * 256 + kc * 32 + q * 8;
#pragma unroll
    for (int ot = 0; ot < 5; ot++) {
      bf16x8 bfr = *(const bf16x8*)(wp + (size_t)ot * 16 * 256);
      acc[ot] = mfma16(af, bfr, acc[ot]);
    }
  }

#pragma unroll
  for (int ot = 0; ot < 5; ot++) {
    int o = oh * 80 + ot * 16 + l15;
    float bias = (o < 32) ? bfv[o] : (o < 64) ? bgv[o - 32] : bhv[o - 64];
    if (oh == 0 && ot < 4) {
      int qk = o >> 5, fr = (o >> 4) & 1, hh = (o >> 3) & 1, e = o & 7;
      size_t base = ((size_t)b * 128 + nt) * 2048 + qk * 1024 + fr * 512 + hh * 256;
      float sc = (o >= 32) ? 1.44269504089f : 1.0f;   // fold log2e into K
#pragma unroll
      for (int r = 0; r < 4; r++) {
        int n_rel = nh * 16 + q * 4 + r;
        qkpk[base + n_rel * 8 + e] = (__bf16)((acc[ot][r] + bias) * sc);
      }
    } else {
#pragma unroll
      for (int r = 0; r < 4; r++) {
        int n_rel = nh * 16 + q * 4 + r;
        ho[(o - 64) * 36 + n_rel] = (__bf16)(acc[ot][r] + bias);
      }
    }
  }
  __syncthreads();
  unsigned short* vpku = (unsigned short*)vpk + (size_t)b * 1048576;
  const unsigned short* hou = (const unsigned short*)ho;
  for (int e = t; e < 4096; e += 512) {
    int c = e >> 4, nn = (e & 15) * 2;
    int n = n0 + nn;
    int jc = n >> 4, hh = (n >> 3) & 1, ee = n & 7;
    unsigned int vv = *(const unsigned int*)(hou + c * 36 + nn);
    *(unsigned int*)(vpku + (((size_t)(jc * 2 + hh) * 256 + c) * 8 + ee)) = vv;
  }
}

// ---------------------------------------------------------------------------
// K2: fused attention — r11 structure (V LDS-staged, P in regs, plain
// spine->pack->PV order), re-gridded for CROSS-BLOCK PHASE OVERLAP.
// R13 verdict: intra-wave interleave can't break the VALU/MFMA/LDS phase
// sequence (compiler serializes; 65us). R11's 4088-cyc chunk = VALU 1226 +
// MFMA 1152 + LDS-port 1728 run in SEQUENCE because ONE block/CU means one
// barrier domain: all waves are in the same phase. Here: 256-thr blocks
// (4 waves, 4 i-tiles), grid 512 -> 2 blocks/CU with INDEPENDENT barriers
// (bi and bi+256 share (b,jp) -> same K/V stream, L1-friendly). Block A's
// VALU phase overlaps block B's PV phase (m114 mechanism). LDS cut to
// 34816 B (epilogue staged in two wave-local half-slices) so 2 blocks fit.
// ---------------------------------------------------------------------------
__global__ __launch_bounds__(256, 2) void attn_kernel(
    const __bf16* __restrict__ qkpk, const __bf16* __restrict__ vpk,
    __bf16* __restrict__ pO, float* __restrict__ Lp) {
  // loop: [0,32768) = V dbuf 2 x 16KB
  // epilogue: 4 waves x [128c][34i] bf16 half-slice = 34816 B (overlaid)
  __shared__ __align__(16) char smem[34816];
  __bf16* Vbuf = (__bf16*)smem;

  const int t = threadIdx.x;
  const int l = t & 63, w = t >> 6;          // 4 waves
  const int h = l >> 5, l31 = l & 31;

  const int bi = blockIdx.x;
  const int xcd = bi & 7;
  const int combo = xcd * 2 + ((bi >> 3) & 1);  // (b,jp) pinned to one XCD
  const int ig = bi >> 4;                       // 0..31
  const int b = combo >> 2, jp = combo & 3;
  const int ti = ig * 4 + w;                    // i-tile 0..127
  const int n0 = ti << 5;

  const __bf16* qkb = qkpk + (size_t)b * 262144;
  const __bf16* vpb = vpk + (size_t)b * 1048576;
  const int jq0 = jp << 10;

  // Q B-frag (lane = col = i), hoisted
  const __bf16* qp = qkb + (size_t)ti * 2048 + h * 256 + l31 * 8;
  const bf16x8 qf0 = *(const bf16x8*)(qp);
  const bf16x8 qf1 = *(const bf16x8*)(qp + 512);

  f32x16 acc[8] = {};                        // [ct] -> c = ct*32 + l31
  float rsum = 0.f;

  const __bf16* kbase = qkb + 1024 + h * 256 + l31 * 8;  // K A-frag base
  const int vfo = h * 2048 + l31 * 8;        // V frag offset within jc-half

  bf16x8 kf0 = *(const bf16x8*)(kbase + (size_t)(jq0 >> 5) * 2048);
  bf16x8 kf1 = *(const bf16x8*)(kbase + (size_t)(jq0 >> 5) * 2048 + 512);

  // ---- prologue: stage V chunk 0 into buf0 (4 stripes, 256 thr) ----
  {
    const __bf16* src = vpb + (size_t)(jq0 >> 4) * 4096;
#pragma unroll
    for (int s = 0; s < 4; s++)
      *(bf16x8*)(Vbuf + s * 2048 + t * 8) = *(const bf16x8*)(src + s * 2048 + t * 8);
  }
  sync_lds();

  // ---- main loop: 32 chunks of 32 j ----
#pragma unroll 1
  for (int ch = 0; ch < 32; ++ch) {
    // issue stage loads for chunk ch+1 (write at bottom - T14)
    bf16x8 sv[4];
    if (ch < 31) {
      const __bf16* src = vpb + (size_t)((jq0 >> 4) + (ch + 1) * 2) * 4096;
#pragma unroll
      for (int s = 0; s < 4; s++)
        sv[s] = *(const bf16x8*)(src + s * 2048 + t * 8);
    }

    // spine: S^T = mfma(K,Q), lane holds P row for i = l31
    f32x16 s = {};
    s = mfma32(kf0, qf0, s);
    s = mfma32(kf1, qf1, s);

    if (ch < 31) {  // K prefetch for next chunk
      const __bf16* kp = kbase + (size_t)((jq0 >> 5) + ch + 1) * 2048;
      kf0 = *(const bf16x8*)(kp);
      kf1 = *(const bf16x8*)(kp + 512);
    }

    // exp2 + rowsum + pack -> PV A-fragments (T12)
    bf16x8 pa0, pa1;
    pack_tile(s, rsum, pa0, pa1);

    // PV: V B-frags from LDS buf[ch&1] (ds_read_b128)
    const __bf16* rb = Vbuf + (ch & 1) * 8192;
#pragma unroll
    for (int ct = 0; ct < 8; ct++) {
      bf16x8 vv = *(const bf16x8*)(rb + vfo + ct * 256);            // jc lo
      acc[ct] = mfma32(pa0, vv, acc[ct]);
    }
#pragma unroll
    for (int ct = 0; ct < 8; ct++) {
      bf16x8 vv = *(const bf16x8*)(rb + 4096 + vfo + ct * 256);     // jc hi
      acc[ct] = mfma32(pa1, vv, acc[ct]);
    }

    // write stage -> other buffer; lgkm-only barrier
    if (ch < 31) {
      __bf16* wb = Vbuf + ((ch + 1) & 1) * 8192;
#pragma unroll
      for (int s = 0; s < 4; s++)
        *(bf16x8*)(wb + s * 2048 + t * 8) = sv[s];
    }
    sync_lds();
  }

  // epilogue: two wave-local half-slices [128c][34i] (4352 elems/wave each).
  // DS pipe is in-order within a wave -> no barriers needed between halves.
  __bf16* stage = (__bf16*)smem + (size_t)w * 4352;
  unsigned short* ob = (unsigned short*)pO + (size_t)(jp * 4 + b) * 1048576 + n0;
  const unsigned short* su = (const unsigned short*)stage;
#pragma unroll 1
  for (int half = 0; half < 2; half++) {
#pragma unroll
    for (int ct2 = 0; ct2 < 4; ct2++) {
      int c0 = ct2 * 32 + l31;                 // local c within half
#pragma unroll
      for (int r = 0; r < 16; r++) {
        int i_loc = (r & 3) + 8 * (r >> 2) + 4 * h;
        stage[c0 * 34 + i_loc] = (__bf16)acc[half * 4 + ct2][r];
      }
    }
    asm volatile("s_waitcnt lgkmcnt(0)" ::: "memory");  // wave-local
#pragma unroll 1
    for (int e = l; e < 2048; e += 64) {
      int c = e >> 4, i2 = (e & 15) * 2;
      unsigned int vv = *(const unsigned int*)(su + c * 34 + i2);
      *(unsigned int*)(ob + (size_t)(half * 128 + c) * 4096 + i2) = vv;
    }
  }

  // rowsum: combine lane halves -> L[i = l31]
  rsum += __shfl_xor(rsum, 32);
  if (l < 32) Lp[(size_t)(jp * 4 + b) * 4096 + n0 + l] = rsum;
}

// ---------------------------------------------------------------------------
// K3: combine partials + normalize + residual.
// ---------------------------------------------------------------------------
__global__ __launch_bounds__(256) void norm_kernel(
    const float* __restrict__ x, const float* __restrict__ gamma_p,
    const __bf16* __restrict__ pO, const float* __restrict__ Lp,
    float* __restrict__ out) {
  const int bc = blockIdx.x;           // b = bc>>8, c = bc&255
  const int b = bc >> 8;
  const float gm = gamma_p[0];
  const float* xr = x + (size_t)bc * 4096;
  float* orow = out + (size_t)bc * 4096;
  const __bf16* pbase = pO + (size_t)bc * 4096;   // +jp*4194304
  const float* lbase = Lp + (size_t)b * 4096;     // +jp*16384

  for (int i0 = threadIdx.x * 4; i0 < 4096; i0 += 1024) {
    float4 xv = *(const float4*)(xr + i0);
    float s0 = 0.f, s1 = 0.f, s2 = 0.f, s3 = 0.f;
    float l0 = 0.f, l1 = 0.f, l2 = 0.f, l3 = 0.f;
#pragma unroll
    for (int jp = 0; jp < 4; jp++) {
      bf16x4 pv = *(const bf16x4*)(pbase + (size_t)jp * 4194304 + i0);
      s0 += (float)pv[0]; s1 += (float)pv[1]; s2 += (float)pv[2]; s3 += (float)pv[3];
      float4 lv = *(const float4*)(lbase + (size_t)jp * 16384 + i0);
      l0 += lv.x; l1 += lv.y; l2 += lv.z; l3 += lv.w;
    }
    float4 ov;
    ov.x = gm * s0 / l0 + xv.x;
    ov.y = gm * s1 / l1 + xv.y;
    ov.z = gm * s2 / l2 + xv.z;
    ov.w = gm * s3 / l3 + xv.w;
    *(float4*)(orow + i0) = ov;
  }
}

// ---------------------------------------------------------------------------
extern "C" void kernel_launch(void* const* d_in, const int* in_sizes, int n_in,
                              void* d_out, int out_size, void* d_ws, size_t ws_size,
                              hipStream_t stream) {
  const float* x   = (const float*)d_in[0];
  const float* Wf  = (const float*)d_in[1];
  const float* bfv = (const float*)d_in[2];
  const float* Wg  = (const float*)d_in[3];
  const float* bgv = (const float*)d_in[4];
  const float* Wh  = (const float*)d_in[5];
  const float* bhv = (const float*)d_in[6];
  const float* gm  = (const float*)d_in[7];
  float* out = (float*)d_out;

  char* ws = (char*)d_ws;
  __bf16* Wb   = (__bf16*)ws;                     //   160 KiB  @ 0
  __bf16* qkpk = (__bf16*)(ws + 262144);          //  2 MiB
  __bf16* vpk  = (__bf16*)(ws + 2359296);         //  8 MiB
  __bf16* pO   = (__bf16*)(ws + 10747904);        // 32 MiB
  float*  Lp   = (float*)(ws + 44302336);         // 256 KiB

  hipLaunchKernelGGL(wcvt_kernel, dim3(320), dim3(256), 0, stream, Wf, Wg, Wh, Wb);
  hipLaunchKernelGGL(proj_kernel, dim3(512), dim3(512), 0, stream,
                     x, bfv, bgv, bhv, Wb, qkpk, vpk);
  hipLaunchKernelGGL(attn_kernel, dim3(512), dim3(256), 0, stream,
                     qkpk, vpk, pO, Lp);
  hipLaunchKernelGGL(norm_kernel, dim3(1024), dim3(256), 0, stream,
                     x, gm, pO, Lp, out);
}